// Round 3
// baseline (123.157 us; speedup 1.0000x reference)
//
#include <hip/hip_runtime.h>
#include <hip/hip_bf16.h>
#include <math.h>

// Problem constants
#define MM 12544   // 64 * 196 patches
#define KK 768     // 16*16*3
#define NN 768     // embedding dim
#define BM 128
#define BN 128
#define BK 64
#define KT 12      // KK/BK
#define MT 98      // MM/BM
#define NT 6       // NN/BN
#define TILE_BYTES (BM*BK*2)   // 16384

#define IM2COL_BLOCKS ((MM * 96) / 256)   // 4704
#define WTPACK_BLOCKS ((NN * 96) / 256)   // 288

typedef __bf16 v8bf __attribute__((ext_vector_type(8)));
typedef float  v4f  __attribute__((ext_vector_type(4)));

// ---------------------------------------------------------------------------
// Phase 1 (merged): im2col+pack for A, transpose+pack for W. Branch is
// wave-uniform (blockIdx-based). Pack layout: [t][kt][r 0..127][g^(r&7)][8]
// bf16 — xor swizzle makes GEMM ds_read_b128 fragment reads conflict-free.
// ---------------------------------------------------------------------------
__global__ __launch_bounds__(256) void pack_kernel(const float* __restrict__ img,
                                                   const float* __restrict__ w,
                                                   __hip_bfloat16* __restrict__ apack,
                                                   __hip_bfloat16* __restrict__ wpack) {
    if (blockIdx.x < IM2COL_BLOCKS) {
        int tid = blockIdx.x * 256 + threadIdx.x;   // 0 .. 12544*96-1
        int gg  = tid % 96;                         // k-group of 8 within row
        int m   = tid / 96;                         // patch index 0..12543
        int b   = m / 196;
        int pm  = m - b * 196;
        int pr  = pm / 14;
        int pc  = pm - pr * 14;
        int k0  = gg * 8;
        int i   = k0 / 48;                          // row within patch
        int rem = k0 - i * 48;                      // multiple of 8, <48
        const float* src = img + (size_t)(((b * 224 + pr * 16 + i) * 224 + pc * 16) * 3 + rem);
        float4 f0 = *(const float4*)src;
        float4 f1 = *(const float4*)(src + 4);
        int mt = m >> 7;
        int r  = m & 127;
        int kt = gg >> 3;
        int g  = gg & 7;
        int gs = g ^ (r & 7);
        union { __hip_bfloat16 h[8]; uint4 u; } o;
        o.h[0] = __float2bfloat16(f0.x); o.h[1] = __float2bfloat16(f0.y);
        o.h[2] = __float2bfloat16(f0.z); o.h[3] = __float2bfloat16(f0.w);
        o.h[4] = __float2bfloat16(f1.x); o.h[5] = __float2bfloat16(f1.y);
        o.h[6] = __float2bfloat16(f1.z); o.h[7] = __float2bfloat16(f1.w);
        *(uint4*)(apack + ((size_t)(mt * KT + kt) * BM + r) * BK + gs * 8) = o.u;
    } else {
        int tid = (blockIdx.x - IM2COL_BLOCKS) * 256 + threadIdx.x;  // 0 .. 768*96-1
        int n   = tid % 768;
        int gg  = tid / 768;
        int k0  = gg * 8;
        float f[8];
#pragma unroll
        for (int j = 0; j < 8; j++) f[j] = w[(size_t)(k0 + j) * NN + n];
        int nt = n >> 7;
        int nr = n & 127;
        int kt = gg >> 3;
        int g  = gg & 7;
        int gs = g ^ (nr & 7);
        union { __hip_bfloat16 h[8]; uint4 u; } o;
#pragma unroll
        for (int j = 0; j < 8; j++) o.h[j] = __float2bfloat16(f[j]);
        *(uint4*)(wpack + ((size_t)(nt * KT + kt) * BN + nr) * BK + gs * 8) = o.u;
    }
}

// ---------------------------------------------------------------------------
// Phase 2: bf16 MFMA GEMM + bias + exact GELU.
// XCD-aware 1D block swizzle: consecutive blockIdx round-robin over the 8
// XCDs, so we place the 6 blocks sharing one mt (same 2.35 MB apack stream)
// at stride 8 -> SAME XCD -> A-tiles served from that XCD's 4 MiB L2 after
// the first fetch instead of 6x from Infinity Cache. wpack (1.2 MB) turns
// L2-resident per XCD. Predicted staging traffic past L2: 226 MB -> ~50 MB.
// ---------------------------------------------------------------------------
__global__ __launch_bounds__(256, 4) void gemm_gelu(const __hip_bfloat16* __restrict__ apack,
                                                    const __hip_bfloat16* __restrict__ wpack,
                                                    const float* __restrict__ bias,
                                                    float* __restrict__ out) {
    __shared__ __align__(16) __hip_bfloat16 As[BM * BK];
    __shared__ __align__(16) __hip_bfloat16 Bs[BN * BK];

    // blk -> (mt, nt): same-mt blocks at stride 8 (same XCD under %8 round-robin)
    int blk = blockIdx.x;
    int mt, nt;
    if (blk < 576) {
        int xcd  = blk & 7;
        int slot = blk >> 3;          // 0..71
        nt = slot % 6;
        mt = (slot / 6) * 8 + xcd;    // 0..95
    } else {
        int r = blk - 576;            // 0..11
        mt = 96 + r / 6;
        nt = r % 6;
    }

    const int tid  = threadIdx.x;
    const int lane = tid & 63;
    const int wave = tid >> 6;
    const int wm   = (wave & 1) * 64;
    const int wn   = (wave >> 1) * 64;
    const int col  = lane & 15;
    const int quad = lane >> 4;
    const int cl7  = col & 7;

    v4f acc[4][4];
    const v4f vzero = {0.f, 0.f, 0.f, 0.f};
#pragma unroll
    for (int a = 0; a < 4; a++)
#pragma unroll
        for (int c = 0; c < 4; c++) acc[a][c] = vzero;

    const char* aT = (const char*)apack + (size_t)mt * KT * TILE_BYTES;
    const char* bT = (const char*)wpack + (size_t)nt * KT * TILE_BYTES;

    for (int kt = 0; kt < KT; kt++) {
        // ---- stage 16KB A-tile + 16KB B-tile (each thread: 4+4 x 16B) ----
#pragma unroll
        for (int p = 0; p < 4; p++) {
            int off = p * 4096 + tid * 16;
            __builtin_amdgcn_global_load_lds(
                (const __attribute__((address_space(1))) void*)(aT + off),
                (__attribute__((address_space(3))) void*)((char*)As + off), 16, 0, 0);
            __builtin_amdgcn_global_load_lds(
                (const __attribute__((address_space(1))) void*)(bT + off),
                (__attribute__((address_space(3))) void*)((char*)Bs + off), 16, 0, 0);
        }
        aT += TILE_BYTES;
        bT += TILE_BYTES;
        __syncthreads();

        // ---- compute: 2 k-steps of 32, 4x4 MFMA tiles per wave ----
#pragma unroll
        for (int ks = 0; ks < 2; ks++) {
            const int gs = (ks * 4 + quad) ^ cl7;
            const v8bf* pa = (const v8bf*)(As + (wm + col) * BK + gs * 8);
            const v8bf* pb = (const v8bf*)(Bs + (wn + col) * BK + gs * 8);
            v8bf af[4], bfr[4];
#pragma unroll
            for (int mi = 0; mi < 4; mi++) af[mi] = pa[mi * 128];   // +2048 B imm
#pragma unroll
            for (int ni = 0; ni < 4; ni++) bfr[ni] = pb[ni * 128];
#pragma unroll
            for (int mi = 0; mi < 4; mi++)
#pragma unroll
                for (int ni = 0; ni < 4; ni++)
                    acc[mi][ni] = __builtin_amdgcn_mfma_f32_16x16x32_bf16(
                        af[mi], bfr[ni], acc[mi][ni], 0, 0, 0);
        }
        __syncthreads();
    }

    // ---- epilogue: bias + exact GELU, coalesced fp32 stores ----
#pragma unroll
    for (int ni = 0; ni < 4; ni++) {
        int n   = nt * 128 + wn + ni * 16 + col;
        float bv = bias[n];
#pragma unroll
        for (int mi = 0; mi < 4; mi++) {
            int rowb = mt * 128 + wm + mi * 16 + quad * 4;
            float* po = out + (size_t)rowb * NN + n;
#pragma unroll
            for (int rg = 0; rg < 4; rg++) {
                float x = acc[mi][ni][rg] + bv;
                float y = 0.5f * x * (1.0f + erff(x * 0.70710678118654752f));
                po[(size_t)rg * NN] = y;
            }
        }
    }
}

extern "C" void kernel_launch(void* const* d_in, const int* in_sizes, int n_in,
                              void* d_out, int out_size, void* d_ws, size_t ws_size,
                              hipStream_t stream) {
    const float* img   = (const float*)d_in[0];   // [64,224,224,3]
    const float* wproj = (const float*)d_in[1];   // [768,768]
    const float* bias  = (const float*)d_in[2];   // [768]
    float* out = (float*)d_out;                   // [64,196,768]

    __hip_bfloat16* apack = (__hip_bfloat16*)d_ws;                       // 19,267,584 B
    __hip_bfloat16* wpack = (__hip_bfloat16*)((char*)d_ws + (size_t)MM * KK * 2);
    // total ws need: 20,447,232 B

    pack_kernel<<<dim3(IM2COL_BLOCKS + WTPACK_BLOCKS), dim3(256), 0, stream>>>(
        img, wproj, apack, wpack);
    gemm_gelu<<<dim3(MT * NT), dim3(256), 0, stream>>>(apack, wpack, bias, out);
}

// Round 4
// 117.824 us; speedup vs baseline: 1.0453x; 1.0453x over previous
//
#include <hip/hip_runtime.h>
#include <hip/hip_bf16.h>
#include <math.h>

// Problem constants
#define MM 12544   // 64 * 196 patches
#define KK 768     // 16*16*3
#define NN 768     // embedding dim
// GEMM tiling: BM=64, BN=256 -> A-pack re-read only NT=3 times (58 MB LLC
// traffic vs 116 at 128x128); B comes from L2 (wpack nt-slice = 0.4 MB).
#define BM 64
#define BN 256
#define BK 64
#define KT 12              // KK/BK
#define MT 196             // MM/BM
#define NT 3               // NN/BN
#define TILE_A_BYTES (BM*BK*2)   // 8192
#define TILE_B_BYTES (BN*BK*2)   // 32768

#define IM2COL_BLOCKS ((MM * 96) / 256)   // 4704
#define WTPACK_BLOCKS ((NN * 96) / 256)   // 288

typedef __bf16 v8bf __attribute__((ext_vector_type(8)));
typedef float  v4f  __attribute__((ext_vector_type(4)));

// ---------------------------------------------------------------------------
// Phase 1 (merged): im2col+pack for A, transpose+pack for W.
// A-pack: [mt 0..195][kt 0..11][r 0..63][g^(r&7)][8] bf16
// W-pack: [nt 0..2][kt 0..11][n 0..255][g^(n&7)][8] bf16
// xor swizzle keeps the GEMM's ds_read_b128 fragment reads conflict-free.
// ---------------------------------------------------------------------------
__global__ __launch_bounds__(256) void pack_kernel(const float* __restrict__ img,
                                                   const float* __restrict__ w,
                                                   __hip_bfloat16* __restrict__ apack,
                                                   __hip_bfloat16* __restrict__ wpack) {
    if (blockIdx.x < IM2COL_BLOCKS) {
        int tid = blockIdx.x * 256 + threadIdx.x;   // 0 .. 12544*96-1
        int gg  = tid % 96;                         // k-group of 8 within row
        int m   = tid / 96;                         // patch index 0..12543
        int b   = m / 196;
        int pm  = m - b * 196;
        int pr  = pm / 14;
        int pc  = pm - pr * 14;
        int k0  = gg * 8;
        int i   = k0 / 48;                          // row within patch
        int rem = k0 - i * 48;                      // multiple of 8, <48
        const float* src = img + (size_t)(((b * 224 + pr * 16 + i) * 224 + pc * 16) * 3 + rem);
        float4 f0 = *(const float4*)src;
        float4 f1 = *(const float4*)(src + 4);
        int mt = m >> 6;        // 64-row tiles
        int r  = m & 63;
        int kt = gg >> 3;
        int g  = gg & 7;
        int gs = g ^ (r & 7);
        union { __hip_bfloat16 h[8]; uint4 u; } o;
        o.h[0] = __float2bfloat16(f0.x); o.h[1] = __float2bfloat16(f0.y);
        o.h[2] = __float2bfloat16(f0.z); o.h[3] = __float2bfloat16(f0.w);
        o.h[4] = __float2bfloat16(f1.x); o.h[5] = __float2bfloat16(f1.y);
        o.h[6] = __float2bfloat16(f1.z); o.h[7] = __float2bfloat16(f1.w);
        *(uint4*)(apack + ((size_t)(mt * KT + kt) * BM + r) * BK + gs * 8) = o.u;
    } else {
        int tid = (blockIdx.x - IM2COL_BLOCKS) * 256 + threadIdx.x;  // 0 .. 768*96-1
        int n   = tid % 768;
        int gg  = tid / 768;
        int k0  = gg * 8;
        float f[8];
#pragma unroll
        for (int j = 0; j < 8; j++) f[j] = w[(size_t)(k0 + j) * NN + n];
        int nt = n >> 8;        // 256-col tiles
        int nr = n & 255;
        int kt = gg >> 3;
        int g  = gg & 7;
        int gs = g ^ (nr & 7);
        union { __hip_bfloat16 h[8]; uint4 u; } o;
#pragma unroll
        for (int j = 0; j < 8; j++) o.h[j] = __float2bfloat16(f[j]);
        *(uint4*)(wpack + ((size_t)(nt * KT + kt) * BN + nr) * BK + gs * 8) = o.u;
    }
}

// Fast GELU: 0.5x(1+tanh(0.79788456(x+0.044715x^3))) = x * E/(E+1), E=e^{2t}.
// v_exp + v_rcp; max deviation from exact erf-GELU ~3e-3 << 0.103 threshold.
__device__ __forceinline__ float gelu_fast(float x) {
    float t2 = 1.5957691216057308f * x * (1.0f + 0.044715f * x * x);  // 2t
    float e  = __expf(t2);
    float r  = __builtin_amdgcn_rcpf(e + 1.0f);
    return x - x * r;   // x*(1 - 1/(E+1)) = x*E/(E+1)
}

// ---------------------------------------------------------------------------
// Phase 2: bf16 MFMA GEMM + bias + fast GELU.
// 64x256 block tile, 256 thr / 4 waves (wave = 64 rows x 64 cols, 1x4 in N).
// LDS 40 KB single-buffered; global_load_lds width-16 staging.
// ---------------------------------------------------------------------------
__global__ __launch_bounds__(256, 3) void gemm_gelu(const __hip_bfloat16* __restrict__ apack,
                                                    const __hip_bfloat16* __restrict__ wpack,
                                                    const float* __restrict__ bias,
                                                    float* __restrict__ out) {
    __shared__ __align__(16) __hip_bfloat16 As[BM * BK];   //  8 KB
    __shared__ __align__(16) __hip_bfloat16 Bs[BN * BK];   // 32 KB

    const int blk = blockIdx.x;
    const int nt  = blk % 3;
    const int mt  = blk / 3;

    const int tid  = threadIdx.x;
    const int lane = tid & 63;
    const int wave = tid >> 6;
    const int wn   = wave * 64;          // wave's N-offset within tile
    const int col  = lane & 15;
    const int quad = lane >> 4;
    const int cl7  = col & 7;

    v4f acc[4][4];
    const v4f vzero = {0.f, 0.f, 0.f, 0.f};
#pragma unroll
    for (int a = 0; a < 4; a++)
#pragma unroll
        for (int c = 0; c < 4; c++) acc[a][c] = vzero;

    const char* aT = (const char*)apack + (size_t)mt * KT * TILE_A_BYTES;
    const char* bT = (const char*)wpack + (size_t)nt * KT * TILE_B_BYTES;

    for (int kt = 0; kt < KT; kt++) {
        // ---- stage 8KB A + 32KB B (each thread: 2 + 8 x 16B) ----
#pragma unroll
        for (int p = 0; p < 2; p++) {
            int off = p * 4096 + tid * 16;
            __builtin_amdgcn_global_load_lds(
                (const __attribute__((address_space(1))) void*)(aT + off),
                (__attribute__((address_space(3))) void*)((char*)As + off), 16, 0, 0);
        }
#pragma unroll
        for (int p = 0; p < 8; p++) {
            int off = p * 4096 + tid * 16;
            __builtin_amdgcn_global_load_lds(
                (const __attribute__((address_space(1))) void*)(bT + off),
                (__attribute__((address_space(3))) void*)((char*)Bs + off), 16, 0, 0);
        }
        aT += TILE_A_BYTES;
        bT += TILE_B_BYTES;
        __syncthreads();

        // ---- compute: 2 k-steps of 32, 4(M) x 4(N) MFMA tiles per wave ----
#pragma unroll
        for (int ks = 0; ks < 2; ks++) {
            const int gs = (ks * 4 + quad) ^ cl7;
            const v8bf* pa = (const v8bf*)(As + col * BK + gs * 8);
            const v8bf* pb = (const v8bf*)(Bs + (wn + col) * BK + gs * 8);
            v8bf af[4], bfr[4];
#pragma unroll
            for (int mi = 0; mi < 4; mi++) af[mi] = pa[mi * 128];   // +2048 B
#pragma unroll
            for (int ni = 0; ni < 4; ni++) bfr[ni] = pb[ni * 128];
#pragma unroll
            for (int mi = 0; mi < 4; mi++)
#pragma unroll
                for (int ni = 0; ni < 4; ni++)
                    acc[mi][ni] = __builtin_amdgcn_mfma_f32_16x16x32_bf16(
                        af[mi], bfr[ni], acc[mi][ni], 0, 0, 0);
        }
        __syncthreads();
    }

    // ---- epilogue: bias + fast GELU, coalesced fp32 stores ----
#pragma unroll
    for (int ni = 0; ni < 4; ni++) {
        int n    = nt * BN + wn + ni * 16 + col;
        float bv = bias[n];
#pragma unroll
        for (int mi = 0; mi < 4; mi++) {
            int rowb = mt * BM + mi * 16 + quad * 4;
            float* po = out + (size_t)rowb * NN + n;
#pragma unroll
            for (int rg = 0; rg < 4; rg++) {
                float x = acc[mi][ni][rg] + bv;
                po[(size_t)rg * NN] = gelu_fast(x);
            }
        }
    }
}

extern "C" void kernel_launch(void* const* d_in, const int* in_sizes, int n_in,
                              void* d_out, int out_size, void* d_ws, size_t ws_size,
                              hipStream_t stream) {
    const float* img   = (const float*)d_in[0];   // [64,224,224,3]
    const float* wproj = (const float*)d_in[1];   // [768,768]
    const float* bias  = (const float*)d_in[2];   // [768]
    float* out = (float*)d_out;                   // [64,196,768]

    __hip_bfloat16* apack = (__hip_bfloat16*)d_ws;                       // 19,267,584 B
    __hip_bfloat16* wpack = (__hip_bfloat16*)((char*)d_ws + (size_t)MM * KK * 2);
    // total ws need: 20,447,232 B

    pack_kernel<<<dim3(IM2COL_BLOCKS + WTPACK_BLOCKS), dim3(256), 0, stream>>>(
        img, wproj, apack, wpack);
    gemm_gelu<<<dim3(MT * NT), dim3(256), 0, stream>>>(apack, wpack, bias, out);
}